// Round 1
// baseline (30270.081 us; speedup 1.0000x reference)
//
#include <hip/hip_runtime.h>

#define S_LEN 16384
#define BATCH 1024
#define HID   64

__device__ __forceinline__ float fast_rcp(float x) {
#if __has_builtin(__builtin_amdgcn_rcpf)
  return __builtin_amdgcn_rcpf(x);
#else
  return 1.0f / x;
#endif
}

// tanh(x) = (e^{2x}-1)/(e^{2x}+1); |pre| stays <~6 here so no clamp needed.
__device__ __forceinline__ float fast_tanh(float x) {
  float e = __expf(x + x);               // v_mul + v_exp_f32
  return (e - 1.0f) * fast_rcp(e + 1.0f);
}

template<int CTRL, int RMASK>
__device__ __forceinline__ float dpp_add(float v) {
  int t = __builtin_amdgcn_update_dpp(0, __float_as_int(v), CTRL, RMASK, 0xF, true);
  return v + __int_as_float(t);
}

// Full 64-lane sum, result broadcast to all lanes via readlane(63).
__device__ __forceinline__ float wave_sum_bcast(float v) {
  v = dpp_add<0x111, 0xF>(v);  // row_shr:1
  v = dpp_add<0x112, 0xF>(v);  // row_shr:2
  v = dpp_add<0x114, 0xF>(v);  // row_shr:4
  v = dpp_add<0x118, 0xF>(v);  // row_shr:8  -> lane15 of each row has row sum
  v = dpp_add<0x142, 0xA>(v);  // row_bcast:15 -> lane31 = r0+r1, lane63 = r2+r3
  v = dpp_add<0x143, 0xC>(v);  // row_bcast:31 -> lane63 = total
  return __int_as_float(__builtin_amdgcn_readlane(__float_as_int(v), 63));
}

__device__ __forceinline__ float deriv_eval(
    float v, float y, float w1v, float w1y, float bb1, float bb2,
    float w3, float bb3, const float* __restrict__ w2c, float* shbuf, int j)
{
  // layer 1: input is (v, y), both wave-uniform
  float pre1 = fmaf(v, w1v, fmaf(y, w1y, bb1));
  float h1 = fast_tanh(pre1);
  // broadcast h1 across the wave through LDS
  shbuf[j] = h1;
  __syncthreads();
  const float4* s4 = (const float4*)shbuf;
  float a0 = bb2, a1 = 0.f, a2 = 0.f, a3 = 0.f;
#pragma unroll
  for (int k = 0; k < HID / 4; ++k) {
    float4 h = s4[k];
    a0 = fmaf(h.x, w2c[4 * k + 0], a0);
    a1 = fmaf(h.y, w2c[4 * k + 1], a1);
    a2 = fmaf(h.z, w2c[4 * k + 2], a2);
    a3 = fmaf(h.w, w2c[4 * k + 3], a3);
  }
  float h2 = fast_tanh((a0 + a1) + (a2 + a3));
  float p = h2 * w3;                     // layer 3 partial product
  return wave_sum_bcast(p) + bb3;        // k value, uniform across wave
}

__global__ __launch_bounds__(64, 1) void rk4_kernel(
    const float* __restrict__ x,
    const float* __restrict__ W1, const float* __restrict__ b1,
    const float* __restrict__ W2, const float* __restrict__ b2,
    const float* __restrict__ W3, const float* __restrict__ b3,
    float* __restrict__ out)
{
  const int j = threadIdx.x;   // hidden unit index
  const int b = blockIdx.x;    // batch element
  __shared__ float sh[2][HID];

  // per-lane weights
  const float w1v = W1[j];          // W1[0][j]
  const float w1y = W1[HID + j];    // W1[1][j]
  const float bb1 = b1[j];
  const float bb2 = b2[j];
  const float w3  = W3[j];          // W3[j][0]
  const float bb3 = b3[0];

  float w2c[HID];                   // column j of W2, in VGPRs
#pragma unroll
  for (int k = 0; k < HID; ++k) w2c[k] = W2[k * HID + j];

  float y = 0.0f;
  // x prefetch, depth 2 (per-wave uniform scalar stream)
  float vcur = x[b];
  float vnex = x[BATCH + b];

#pragma unroll 1
  for (int s = 0; s < S_LEN; ++s) {
    float v = vcur;
    vcur = vnex;
    int sp = (s + 2 < S_LEN) ? (s + 2) : (S_LEN - 1);
    vnex = x[(size_t)sp * BATCH + b];

    float k1 = deriv_eval(v, y,                    w1v, w1y, bb1, bb2, w3, bb3, w2c, sh[0], j);
    float k2 = deriv_eval(v, fmaf(0.5f, k1, y),    w1v, w1y, bb1, bb2, w3, bb3, w2c, sh[1], j);
    float k3 = deriv_eval(v, fmaf(0.5f, k2, y),    w1v, w1y, bb1, bb2, w3, bb3, w2c, sh[0], j);
    float k4 = deriv_eval(v, y + k3,               w1v, w1y, bb1, bb2, w3, bb3, w2c, sh[1], j);

    y = fmaf((k1 + k4) + 2.0f * (k2 + k3), 1.0f / 6.0f, y);
    if (j == 0) out[(size_t)s * BATCH + b] = y;
  }
}

extern "C" void kernel_launch(void* const* d_in, const int* in_sizes, int n_in,
                              void* d_out, int out_size, void* d_ws, size_t ws_size,
                              hipStream_t stream) {
  const float* x  = (const float*)d_in[0];
  const float* W1 = (const float*)d_in[1];
  const float* b1 = (const float*)d_in[2];
  const float* W2 = (const float*)d_in[3];
  const float* b2 = (const float*)d_in[4];
  const float* W3 = (const float*)d_in[5];
  const float* b3 = (const float*)d_in[6];
  float* out = (float*)d_out;

  rk4_kernel<<<BATCH, HID, 0, stream>>>(x, W1, b1, W2, b2, W3, b3, out);
}

// Round 2
// 27210.098 us; speedup vs baseline: 1.1125x; 1.1125x over previous
//
#include <hip/hip_runtime.h>

#define S_LEN 16384
#define BATCH 1024
#define HID   64
#define SBLK  64   // steps per I/O stripe (== wavefront size)

__device__ __forceinline__ float fast_rcp(float x) {
#if __has_builtin(__builtin_amdgcn_rcpf)
  return __builtin_amdgcn_rcpf(x);
#else
  return 1.0f / x;
#endif
}

__device__ __forceinline__ float fast_exp2(float x) {
#if __has_builtin(__builtin_amdgcn_exp2f)
  return __builtin_amdgcn_exp2f(x);
#else
  return __expf(x * 0.69314718055994531f);
#endif
}

template<int CTRL, int RMASK>
__device__ __forceinline__ float dpp_add(float v) {
  int t = __builtin_amdgcn_update_dpp(0, __float_as_int(v), CTRL, RMASK, 0xF, true);
  return v + __int_as_float(t);
}

// Full 64-lane sum, broadcast to all lanes via readlane(63).
__device__ __forceinline__ float wave_sum_bcast(float v) {
  v = dpp_add<0x111, 0xF>(v);  // row_shr:1
  v = dpp_add<0x112, 0xF>(v);  // row_shr:2
  v = dpp_add<0x114, 0xF>(v);  // row_shr:4
  v = dpp_add<0x118, 0xF>(v);  // row_shr:8
  v = dpp_add<0x142, 0xA>(v);  // row_bcast:15
  v = dpp_add<0x143, 0xC>(v);  // row_bcast:31
  return __int_as_float(__builtin_amdgcn_readlane(__float_as_int(v), 63));
}

// Single wave per block: lanes are lockstep, so no s_barrier needed — only
// LDS-op drain before cross-lane reads.
__device__ __forceinline__ void lds_fence() {
  asm volatile("s_waitcnt lgkmcnt(0)" ::: "memory");
}

// All layer-1/2 weights and biases pre-scaled by 2*log2(e) so that
// tanh(p) = 1 - 2/(2^(p_scaled) + 1): exp2 -> add -> rcp -> fma, 4 deps.
__device__ __forceinline__ float deriv_eval(
    float pv, float yeff, float w1y_s, float bb2_s, float w3v, float bb3,
    const float* __restrict__ w2c, float* shbuf, int j)
{
  float pre1 = fmaf(yeff, w1y_s, pv);
  float e1 = fast_exp2(pre1);
  float h1 = fmaf(-2.0f, fast_rcp(e1 + 1.0f), 1.0f);
  shbuf[j] = h1;
  lds_fence();
  const float4* s4 = (const float4*)shbuf;
  float a0 = bb2_s, a1 = 0.f, a2 = 0.f, a3 = 0.f;
#pragma unroll
  for (int k = 0; k < HID / 4; ++k) {
    float4 h = s4[k];
    a0 = fmaf(h.x, w2c[4 * k + 0], a0);
    a1 = fmaf(h.y, w2c[4 * k + 1], a1);
    a2 = fmaf(h.z, w2c[4 * k + 2], a2);
    a3 = fmaf(h.w, w2c[4 * k + 3], a3);
  }
  float e2 = fast_exp2((a0 + a1) + (a2 + a3));
  float h2 = fmaf(-2.0f, fast_rcp(e2 + 1.0f), 1.0f);
  return wave_sum_bcast(h2 * w3v) + bb3;
}

__global__ __launch_bounds__(64, 1) void rk4_kernel(
    const float* __restrict__ x,
    const float* __restrict__ W1, const float* __restrict__ b1,
    const float* __restrict__ W2, const float* __restrict__ b2,
    const float* __restrict__ W3, const float* __restrict__ b3,
    float* __restrict__ out)
{
  const int j = threadIdx.x;   // hidden unit / stripe lane
  const int b = blockIdx.x;    // batch element
  __shared__ float sh[2][HID];

  const float SC = 2.8853900817779268f;  // 2*log2(e)
  const float w1v_s = SC * W1[j];        // W1[0][j]
  const float w1y_s = SC * W1[HID + j];  // W1[1][j]
  const float b1_s  = SC * b1[j];
  const float bb2_s = SC * b2[j];
  const float w3v   = W3[j];             // W3[j][0]
  const float bb3   = b3[0];

  float w2c[HID];                        // column j of W2 (pre-scaled)
#pragma unroll
  for (int k = 0; k < HID; ++k) w2c[k] = SC * W2[k * HID + j];

  float y = 0.0f;
  // lane-striped x: lane r holds x[s0 + r][b]; one load per 64 steps
  float xcur = x[(size_t)j * BATCH + b];
  float ybuf = 0.0f;
  size_t obase = (size_t)j * BATCH + b;  // lane's output slot in current stripe

#pragma unroll 1
  for (int blk = 0; blk < S_LEN / SBLK; ++blk) {
    int pf = blk * SBLK + SBLK + j;
    if (pf >= S_LEN) pf = S_LEN - 1;     // clamped prefetch for last stripe
    float xnext = x[(size_t)pf * BATCH + b];

#pragma unroll 1
    for (int t = 0; t < SBLK; ++t) {
      float xv = __int_as_float(__builtin_amdgcn_readlane(__float_as_int(xcur), t));
      float pv = fmaf(xv, w1v_s, b1_s);  // shared by all 4 RK stages
      float k1 = deriv_eval(pv, y,                 w1y_s, bb2_s, w3v, bb3, w2c, sh[0], j);
      float k2 = deriv_eval(pv, fmaf(0.5f, k1, y), w1y_s, bb2_s, w3v, bb3, w2c, sh[1], j);
      float k3 = deriv_eval(pv, fmaf(0.5f, k2, y), w1y_s, bb2_s, w3v, bb3, w2c, sh[0], j);
      float k4 = deriv_eval(pv, y + k3,            w1y_s, bb2_s, w3v, bb3, w2c, sh[1], j);
      y = fmaf((k1 + k4) + 2.0f * (k2 + k3), 1.0f / 6.0f, y);
      if (t == j) ybuf = y;              // stash into this lane's stripe slot
    }
    out[obase] = ybuf;                   // one scatter store per 64 steps
    obase += (size_t)SBLK * BATCH;
    xcur = xnext;
  }
}

extern "C" void kernel_launch(void* const* d_in, const int* in_sizes, int n_in,
                              void* d_out, int out_size, void* d_ws, size_t ws_size,
                              hipStream_t stream) {
  const float* x  = (const float*)d_in[0];
  const float* W1 = (const float*)d_in[1];
  const float* b1 = (const float*)d_in[2];
  const float* W2 = (const float*)d_in[3];
  const float* b2 = (const float*)d_in[4];
  const float* W3 = (const float*)d_in[5];
  const float* b3 = (const float*)d_in[6];
  float* out = (float*)d_out;

  rk4_kernel<<<BATCH, HID, 0, stream>>>(x, W1, b1, W2, b2, W3, b3, out);
}

// Round 6
// 26487.854 us; speedup vs baseline: 1.1428x; 1.0273x over previous
//
#include <hip/hip_runtime.h>

#define S_LEN 16384
#define BATCH 1024
#define HID   64
#define SBLK  64   // steps per I/O stripe (== wavefront size)

__device__ __forceinline__ float fast_rcp(float x) {
#if __has_builtin(__builtin_amdgcn_rcpf)
  return __builtin_amdgcn_rcpf(x);
#else
  return 1.0f / x;
#endif
}

__device__ __forceinline__ float fast_exp2(float x) {
#if __has_builtin(__builtin_amdgcn_exp2f)
  return __builtin_amdgcn_exp2f(x);
#else
  return __expf(x * 0.69314718055994531f);
#endif
}

// ---- DPP reduce (proven R1/R2) --------------------------------------------
template<int CTRL, int RMASK>
__device__ __forceinline__ float dpp_add(float v) {
  int t = __builtin_amdgcn_update_dpp(0, __float_as_int(v), CTRL, RMASK, 0xF, true);
  return v + __int_as_float(t);
}

// Full 64-lane sum, broadcast to all lanes via readlane(63).
__device__ __forceinline__ float wave_sum_bcast(float v) {
  v = dpp_add<0x111, 0xF>(v);  // row_shr:1
  v = dpp_add<0x112, 0xF>(v);  // row_shr:2
  v = dpp_add<0x114, 0xF>(v);  // row_shr:4
  v = dpp_add<0x118, 0xF>(v);  // row_shr:8
  v = dpp_add<0x142, 0xA>(v);  // row_bcast:15
  v = dpp_add<0x143, 0xC>(v);  // row_bcast:31
  return __int_as_float(__builtin_amdgcn_readlane(__float_as_int(v), 63));
}

__device__ __forceinline__ float rdlane(float v, int l) {
  return __int_as_float(__builtin_amdgcn_readlane(__float_as_int(v), l));
}

// Single wave per block: lanes lockstep — only LDS-op drain needed, no barrier.
// (Proven correct in R2.)
__device__ __forceinline__ void lds_fence() {
  asm volatile("s_waitcnt lgkmcnt(0)" ::: "memory");
}

// tanh(z) = 1 - 2/(e^{2z}+1); pre-activations carry the 2*log2(e) scale so
// e^{2z} = exp2(pre). The "1 - 2*" is folded into the NEXT layer's weights:
// we broadcast r = rcp(exp2(pre)+1) and use wv[k] = -2*SC*W2[k][j], with the
// bias absorbing SC*(b2[j] + colsum_j(W2)). Algebraically exact.
// Saturation-safe: exp2->inf => r->0 => h=+1; exp2->0 => r->1 => h=-1.
__device__ __forceinline__ float deriv_eval(
    float pv, float yv, float w1y_s, float w2b, float w3v, float w3m2,
    float bb3, const float (&wv)[HID], float* shbuf, int j)
{
  float pre1 = fmaf(yv, w1y_s, pv);
  float r1 = fast_rcp(fast_exp2(pre1) + 1.0f);   // lane j holds unit j
  shbuf[j] = r1;
  lds_fence();
  const float4* s4 = (const float4*)shbuf;
  float a0 = w2b, a1 = 0.f, a2 = 0.f, a3 = 0.f;
#pragma unroll
  for (int k = 0; k < HID / 4; ++k) {
    float4 h = s4[k];
    a0 = fmaf(h.x, wv[4 * k + 0], a0);
    a1 = fmaf(h.y, wv[4 * k + 1], a1);
    a2 = fmaf(h.z, wv[4 * k + 2], a2);
    a3 = fmaf(h.w, wv[4 * k + 3], a3);
  }
  float pre2 = (a0 + a1) + (a2 + a3);
  float r2 = fast_rcp(fast_exp2(pre2) + 1.0f);
  float p = fmaf(w3m2, r2, w3v);                 // h2 * W3[j]
  return wave_sum_bcast(p) + bb3;                // k value, uniform
}

__global__ __launch_bounds__(64, 1) void rk4_kernel(
    const float* __restrict__ x,
    const float* __restrict__ W1, const float* __restrict__ b1,
    const float* __restrict__ W2, const float* __restrict__ b2,
    const float* __restrict__ W3, const float* __restrict__ b3,
    float* __restrict__ out)
{
  const int j = threadIdx.x;   // hidden unit / lane index
  const int b = blockIdx.x;    // batch element
  __shared__ float sh[2][HID];

  const float SC = 2.8853900817779268f;  // 2*log2(e)
  const float w1v_s = SC * W1[j];        // W1[0][j]
  const float w1y_s = SC * W1[HID + j];  // W1[1][j]
  const float b1_s  = SC * b1[j];
  const float w3v   = W3[j];             // W3[j][0]
  const float w3m2  = -2.0f * w3v;
  const float bb3   = b3[0];

  // Column j of W2 folded with -2*SC, PINNED in VGPRs via opaque asm so the
  // compiler cannot spill/rematerialize it inside the serial loop
  // (R1/R2: VGPR_Count=44/52 => W2 was being re-fetched every deriv).
  float wv[HID];
  float colsum = 0.f;
#pragma unroll
  for (int k = 0; k < HID; ++k) {
    float w = W2[k * HID + j];
    colsum += w;
    wv[k] = -2.0f * SC * w;
  }
#pragma unroll
  for (int k = 0; k < HID; ++k) asm volatile("" : "+v"(wv[k]));
  const float w2b = SC * (b2[j] + colsum);

  float y = 0.0f;
  // lane-striped x: lane r holds x[s0 + r][b]; one load per 64 steps
  float xcur = x[(size_t)j * BATCH + b];
  float ybuf = 0.0f;
  size_t obase = (size_t)j * BATCH + b;  // lane's output slot in current stripe

#pragma unroll 1
  for (int blk = 0; blk < S_LEN / SBLK; ++blk) {
    int pf = blk * SBLK + SBLK + j;
    if (pf >= S_LEN) pf = S_LEN - 1;     // clamped prefetch for last stripe
    float xnext = x[(size_t)pf * BATCH + b];

#pragma unroll 1
    for (int t = 0; t < SBLK; ++t) {
      float xv = rdlane(xcur, t);
      float pv = fmaf(xv, w1v_s, b1_s);  // shared by all 4 RK stages
      float k1 = deriv_eval(pv, y,                 w1y_s, w2b, w3v, w3m2, bb3, wv, sh[0], j);
      float k2 = deriv_eval(pv, fmaf(0.5f, k1, y), w1y_s, w2b, w3v, w3m2, bb3, wv, sh[1], j);
      float k3 = deriv_eval(pv, fmaf(0.5f, k2, y), w1y_s, w2b, w3v, w3m2, bb3, wv, sh[0], j);
      float k4 = deriv_eval(pv, y + k3,            w1y_s, w2b, w3v, w3m2, bb3, wv, sh[1], j);
      y = fmaf((k1 + k4) + 2.0f * (k2 + k3), 1.0f / 6.0f, y);
      if (t == j) ybuf = y;              // stash into this lane's stripe slot
    }
    out[obase] = ybuf;                   // one scatter store per 64 steps
    obase += (size_t)SBLK * BATCH;
    xcur = xnext;
  }
}

extern "C" void kernel_launch(void* const* d_in, const int* in_sizes, int n_in,
                              void* d_out, int out_size, void* d_ws, size_t ws_size,
                              hipStream_t stream) {
  const float* x  = (const float*)d_in[0];
  const float* W1 = (const float*)d_in[1];
  const float* b1 = (const float*)d_in[2];
  const float* W2 = (const float*)d_in[3];
  const float* b2 = (const float*)d_in[4];
  const float* W3 = (const float*)d_in[5];
  const float* b3 = (const float*)d_in[6];
  float* out = (float*)d_out;

  rk4_kernel<<<BATCH, HID, 0, stream>>>(x, W1, b1, W2, b2, W3, b3, out);
}